// Round 16
// baseline (327.506 us; speedup 1.0000x reference)
//
#include <hip/hip_runtime.h>

#define DEV static __device__ __forceinline__

typedef float  f32x2 __attribute__((ext_vector_type(2)));
typedef float  f32x4 __attribute__((ext_vector_type(4)));
typedef float  f32x8 __attribute__((ext_vector_type(8)));
typedef __bf16 bf16x8 __attribute__((ext_vector_type(8)));
typedef unsigned short u16x8 __attribute__((ext_vector_type(8)));
typedef int    i32x4 __attribute__((ext_vector_type(4)));

// ---------- helpers ----------
DEV unsigned short f2bf(float f) {              // RNE f32 -> bf16 bits
  unsigned u = __builtin_bit_cast(unsigned, f);
  u += 0x7FFFu + ((u >> 16) & 1u);
  return (unsigned short)(u >> 16);
}
DEV float bf2f(unsigned short h) {
  unsigned u = (unsigned)h << 16;
  return __builtin_bit_cast(float, u);
}

DEV f32x4 mfma16(u16x8 a, u16x8 b, f32x4 c) {
  return __builtin_amdgcn_mfma_f32_16x16x32_bf16(
      __builtin_bit_cast(bf16x8, a), __builtin_bit_cast(bf16x8, b), c, 0, 0, 0);
}
DEV i32x4 mfma8(uint4 a, uint4 b, i32x4 c) {    // i8 16x16x64
  return __builtin_amdgcn_mfma_i32_16x16x64_i8(
      __builtin_bit_cast(i32x4, a), __builtin_bit_cast(i32x4, b), c, 0, 0, 0);
}

// raw hardware exp2 (v_exp_f32: D = 2^S0)
DEV float exp2_hw(float x) { float r; asm("v_exp_f32 %0, %1" : "=v"(r) : "v"(x)); return r; }
DEV float sig_fast(float x) { return __builtin_amdgcn_rcpf(1.f + exp2_hw(-1.44269504f * x)); }
DEV float tanh_fast(float x) { return 1.f - 2.f * __builtin_amdgcn_rcpf(exp2_hw(2.88539008f * x) + 1.f); }

// packed dual-FMA: acc.{x,y} += a.{x,y} * b.{x,y}
DEV void pkfma(f32x2& acc, f32x2 a, f32x2 b) {
  asm("v_pk_fma_f32 %0, %1, %2, %0" : "+v"(acc) : "v"(a), "v"(b));
}

// 16 bits -> 16 bytes {0,1} (byte i = bit i): nibble-multiply spread
DEV uint4 expand16(unsigned hw) {
  uint4 r;
  r.x = ((hw         & 0xFu) * 0x00204081u) & 0x01010101u;
  r.y = (((hw >> 4)  & 0xFu) * 0x00204081u) & 0x01010101u;
  r.z = (((hw >> 8)  & 0xFu) * 0x00204081u) & 0x01010101u;
  r.w = (((hw >> 12) & 0xFu) * 0x00204081u) & 0x01010101u;
  return r;
}

// split 8 f32 -> hi/lo bf16 fragments (v = hi + lo exactly to ~2^-17)
DEV void split8(const float* p, u16x8& h, u16x8& l) {
  union { f32x4 q[2]; f32x8 o; } u;
  u.q[0] = *reinterpret_cast<const f32x4*>(p);
  u.q[1] = *reinterpret_cast<const f32x4*>(p + 4);
  #pragma unroll
  for (int i = 0; i < 8; ++i) {
    float v = u.o[i];
    unsigned short hb = f2bf(v);
    h[i] = hb;
    l[i] = f2bf(v - bf2f(hb));
  }
}

// ---------- split-precision GEMM: C = act(A[32768,K] @ W[K,NC] + b) ----------
template <int K, int NC, int ACT>
__global__ __launch_bounds__(256) void k_ff(
    const float* __restrict__ A1, const float* __restrict__ A2,
    const float* __restrict__ W1, const float* __restrict__ W2,
    const float* __restrict__ b1, const float* __restrict__ b2,
    float* __restrict__ C, int ldC, long brCstride) {
  int bid = blockIdx.x;
  int br = bid >> 8, rbk = bid & 255;
  const float* A = br ? A2 : A1;
  const float* W = br ? W2 : W1;
  const float* bias = br ? b2 : b1;

  __shared__ __attribute__((aligned(16))) unsigned short WTh[NC][K + 8];
  __shared__ __attribute__((aligned(16))) unsigned short WTl[NC][K + 8];
  for (int idx = threadIdx.x; idx < K * NC; idx += 256) {
    int k = idx / NC, c = idx % NC;
    float w = W[idx];
    unsigned short hb = f2bf(w);
    WTh[c][k] = hb;
    WTl[c][k] = f2bf(w - bf2f(hb));
  }
  __syncthreads();

  int wave = threadIdx.x >> 6, lane = threadIdx.x & 63;
  int l15 = lane & 15, g = lane >> 4;
  int row0 = rbk * 128 + wave * 32;

  f32x4 acc[2][NC / 16] = {};
  for (int kk = 0; kk < K; kk += 32) {
    u16x8 ah[2], al[2];
    #pragma unroll
    for (int rt = 0; rt < 2; ++rt)
      split8(A + (size_t)(row0 + rt * 16 + l15) * K + kk + g * 8, ah[rt], al[rt]);
    #pragma unroll
    for (int ct = 0; ct < NC / 16; ++ct) {
      u16x8 wh = *reinterpret_cast<const u16x8*>(&WTh[ct * 16 + l15][kk + g * 8]);
      u16x8 wl = *reinterpret_cast<const u16x8*>(&WTl[ct * 16 + l15][kk + g * 8]);
      #pragma unroll
      for (int rt = 0; rt < 2; ++rt) {
        acc[rt][ct] = mfma16(ah[rt], wh, acc[rt][ct]);
        acc[rt][ct] = mfma16(al[rt], wh, acc[rt][ct]);
        acc[rt][ct] = mfma16(ah[rt], wl, acc[rt][ct]);
      }
    }
  }

  float bv[NC / 16];
  #pragma unroll
  for (int ct = 0; ct < NC / 16; ++ct) bv[ct] = bias[ct * 16 + l15];
  #pragma unroll
  for (int rt = 0; rt < 2; ++rt)
    #pragma unroll
    for (int ct = 0; ct < NC / 16; ++ct)
      #pragma unroll
      for (int r = 0; r < 4; ++r) {
        float v = acc[rt][ct][r] + bv[ct];
        if (ACT) v = fmaxf(v, 0.f);
        C[(size_t)br * brCstride +
          (size_t)(row0 + rt * 16 + g * 4 + r) * ldC + ct * 16 + l15] = v;
      }
}

// ---------- FRONT: blocks 0..15   = LSTM (4 waves; each wave = 2 seqs,
//                                   4-gates-per-lane, NO cross-lane in chain)
//                   blocks 16..271 = pack cfg->bits
//                   blocks 272..783= fused lit-MLP
// LDS padded past 80KB -> 1 block/CU: LSTM CUs isolated from pack/MLP. ----------
__global__ __launch_bounds__(256) void k_front(
    const float* __restrict__ xk,
    const float* __restrict__ lrk1, const float* __restrict__ lrk2,
    float* __restrict__ bb,
    const int* __restrict__ cfg1, const int* __restrict__ cfg2,
    unsigned* __restrict__ bits,
    const float* __restrict__ lit1, const float* __restrict__ lit2,
    const float* __restrict__ d1w1, const float* __restrict__ d1w2,
    const float* __restrict__ d1b1, const float* __restrict__ d1b2,
    const float* __restrict__ d2w1, const float* __restrict__ d2w2,
    const float* __restrict__ d2b1, const float* __restrict__ d2b2) {
  __shared__ __attribute__((aligned(16))) unsigned short WT1h[64][136];
  __shared__ __attribute__((aligned(16))) unsigned short WT1l[64][136];
  __shared__ __attribute__((aligned(16))) unsigned short WT2h[32][72];
  __shared__ __attribute__((aligned(16))) unsigned short WT2l[32][72];
  __shared__ __attribute__((aligned(16))) float H1[128][68];
  __shared__ __attribute__((aligned(16))) float sh[4][2][32];
  __shared__ __attribute__((aligned(16))) float lds_pad[600];  // -> >80KB, 1 blk/CU

  int bid = blockIdx.x;
  int wave = threadIdx.x >> 6, lane = threadIdx.x & 63;
  if (bid == 0x3FFFFFFF) ((volatile float*)lds_pad)[threadIdx.x & 511] = 1.f;

  if (bid < 16) {
    // ---- LSTM: lanes 0..31 = seq (br0, b=gb); lanes 32..63 = seq (br1, b=gb).
    //      Each lane computes ALL 4 gate dots for its unit u -> c,h update is
    //      lane-local; only cross-lane dep is h-broadcast via wave-private LDS
    //      (1 ds_write + 8 broadcast ds_read_b128). No shfl in the chain. ----
    int gb = bid * 4 + wave;                  // 0..63 = batch index
    int u = lane & 31, half = lane >> 5;      // half = branch
    const float* rkp = half ? lrk2 : lrk1;    // [32][128], gate cols i,f,g,o
    f32x2 rki[16], rkf[16], rkg[16], rko[16];
    #pragma unroll
    for (int k2 = 0; k2 < 16; ++k2) {
      const float* r0 = rkp + (2 * k2) * 128;
      const float* r1 = rkp + (2 * k2 + 1) * 128;
      rki[k2] = f32x2{r0[u],      r1[u]};
      rkf[k2] = f32x2{r0[32 + u], r1[32 + u]};
      rkg[k2] = f32x2{r0[64 + u], r1[64 + u]};
      rko[k2] = f32x2{r0[96 + u], r1[96 + u]};
    }
    float* shw = &sh[wave][half][0];
    shw[u] = 0.f;

    const float* xkb = xk + ((size_t)half * 32768 + (size_t)gb * 512) * 128;
    float* bbo = bb + ((size_t)half * 32768 + (size_t)gb * 512) * 64 + 32;
    float cst = 0.f;

    // 4-deep prefetch of the 4 gate inputs; reads past t=511 (to 515) stay
    // inside the workspace allocation -> safe, values never consumed.
    float zi0 = xkb[0 * 128 + u], zf0 = xkb[0 * 128 + 32 + u];
    float zg0 = xkb[0 * 128 + 64 + u], zo0 = xkb[0 * 128 + 96 + u];
    float zi1 = xkb[1 * 128 + u], zf1 = xkb[1 * 128 + 32 + u];
    float zg1 = xkb[1 * 128 + 64 + u], zo1 = xkb[1 * 128 + 96 + u];
    float zi2 = xkb[2 * 128 + u], zf2 = xkb[2 * 128 + 32 + u];
    float zg2 = xkb[2 * 128 + 64 + u], zo2 = xkb[2 * 128 + 96 + u];
    float zi3 = xkb[3 * 128 + u], zf3 = xkb[3 * 128 + 32 + u];
    float zg3 = xkb[3 * 128 + 64 + u], zo3 = xkb[3 * 128 + 96 + u];

    union HQ { f32x4 q; f32x2 p[2]; };

#define LSTM_STEP(T, ZI, ZF, ZG, ZO) {                                  \
    float ai = ZI, af = ZF, ag = ZG, ao = ZO;                           \
    ZI = xkb[((T) + 4) * 128 + u];                                      \
    ZF = xkb[((T) + 4) * 128 + 32 + u];                                 \
    ZG = xkb[((T) + 4) * 128 + 64 + u];                                 \
    ZO = xkb[((T) + 4) * 128 + 96 + u];                                 \
    HQ hq[8];                                                           \
    _Pragma("unroll")                                                   \
    for (int j = 0; j < 8; ++j)                                         \
      hq[j].q = *reinterpret_cast<const f32x4*>(&shw[j * 4]);           \
    f32x2 AI = {0.f, 0.f}, AF = {0.f, 0.f};                             \
    f32x2 AG = {0.f, 0.f}, AO = {0.f, 0.f};                             \
    _Pragma("unroll")                                                   \
    for (int j = 0; j < 8; ++j) {                                       \
      pkfma(AI, hq[j].p[0], rki[2 * j]);                                \
      pkfma(AF, hq[j].p[0], rkf[2 * j]);                                \
      pkfma(AG, hq[j].p[0], rkg[2 * j]);                                \
      pkfma(AO, hq[j].p[0], rko[2 * j]);                                \
      pkfma(AI, hq[j].p[1], rki[2 * j + 1]);                            \
      pkfma(AF, hq[j].p[1], rkf[2 * j + 1]);                            \
      pkfma(AG, hq[j].p[1], rkg[2 * j + 1]);                            \
      pkfma(AO, hq[j].p[1], rko[2 * j + 1]);                            \
    }                                                                   \
    ai += AI.x + AI.y; af += AF.x + AF.y;                               \
    ag += AG.x + AG.y; ao += AO.x + AO.y;                               \
    float si = sig_fast(ai), sf = sig_fast(af);                         \
    float tg = tanh_fast(ag), so = sig_fast(ao);                        \
    cst = sf * cst + si * tg;                                           \
    float hv = so * tanh_fast(cst);                                     \
    shw[u] = hv;                                                        \
    bbo[(T) * 64 + u] = hv;                                             \
  }

    for (int tb = 0; tb < 512; tb += 4) {
      LSTM_STEP(tb + 0, zi0, zf0, zg0, zo0)
      LSTM_STEP(tb + 1, zi1, zf1, zg1, zo1)
      LSTM_STEP(tb + 2, zi2, zf2, zg2, zo2)
      LSTM_STEP(tb + 3, zi3, zf3, zg3, zo3)
    }
#undef LSTM_STEP
    return;
  }

  if (bid < 272) {
    // ---- pack: 65536 threads x 16 words, coalesced ----
    unsigned worker = (unsigned)(bid - 16) * 256u + threadIdx.x;
    #pragma unroll
    for (int j = 0; j < 16; ++j) {
      unsigned idx = worker + (unsigned)j * 65536u;   // 0 .. 1048575
      unsigned br2 = idx >> 19;
      unsigned rem = idx & 524287u;
      const int4* p = reinterpret_cast<const int4*>(br2 ? cfg2 : cfg1) + rem * 8;
      unsigned m = 0;
      #pragma unroll
      for (int q = 0; q < 8; ++q) {
        int4 v = p[q];
        unsigned base = q * 4;
        m |= ((unsigned)v.x & 1u) << (base + 0);
        m |= ((unsigned)v.y & 1u) << (base + 1);
        m |= ((unsigned)v.z & 1u) << (base + 2);
        m |= ((unsigned)v.w & 1u) << (base + 3);
      }
      bits[idx] = m;
    }
    return;
  }

  // ---- fused lit-MLP: 128 rows per block ----
  int bid2 = bid - 272;                       // 0..511
  int br = bid2 >> 8, rbk = bid2 & 255;
  const float* lit = br ? lit2 : lit1;
  const float* W1  = br ? d1w2 : d1w1;        // [128][64]
  const float* B1  = br ? d1b2 : d1b1;
  const float* W2  = br ? d2w2 : d2w1;        // [64][32]
  const float* B2  = br ? d2b2 : d2b1;

  for (int idx = threadIdx.x; idx < 8192; idx += 256) {
    int k = idx >> 6, c = idx & 63;
    float w = W1[idx];
    unsigned short hb = f2bf(w);
    WT1h[c][k] = hb;
    WT1l[c][k] = f2bf(w - bf2f(hb));
  }
  for (int idx = threadIdx.x; idx < 2048; idx += 256) {
    int k = idx >> 5, c = idx & 31;
    float w = W2[idx];
    unsigned short hb = f2bf(w);
    WT2h[c][k] = hb;
    WT2l[c][k] = f2bf(w - bf2f(hb));
  }
  __syncthreads();

  int l15 = lane & 15, g = lane >> 4;
  int row0 = rbk * 128 + wave * 32;

  f32x4 acc[2][4] = {};
  #pragma unroll
  for (int kk = 0; kk < 128; kk += 32) {
    u16x8 ah[2], al[2];
    #pragma unroll
    for (int rt = 0; rt < 2; ++rt)
      split8(lit + (size_t)(row0 + rt * 16 + l15) * 128 + kk + g * 8, ah[rt], al[rt]);
    #pragma unroll
    for (int ct = 0; ct < 4; ++ct) {
      u16x8 wh = *reinterpret_cast<const u16x8*>(&WT1h[ct * 16 + l15][kk + g * 8]);
      u16x8 wl = *reinterpret_cast<const u16x8*>(&WT1l[ct * 16 + l15][kk + g * 8]);
      #pragma unroll
      for (int rt = 0; rt < 2; ++rt) {
        acc[rt][ct] = mfma16(ah[rt], wh, acc[rt][ct]);
        acc[rt][ct] = mfma16(al[rt], wh, acc[rt][ct]);
        acc[rt][ct] = mfma16(ah[rt], wl, acc[rt][ct]);
      }
    }
  }
  #pragma unroll
  for (int ct = 0; ct < 4; ++ct) {
    float bv = B1[ct * 16 + l15];
    #pragma unroll
    for (int rt = 0; rt < 2; ++rt)
      #pragma unroll
      for (int r = 0; r < 4; ++r)
        H1[wave * 32 + rt * 16 + g * 4 + r][ct * 16 + l15] =
            fmaxf(acc[rt][ct][r] + bv, 0.f);
  }
  // layer 2 (wave-local H1 rows; same-wave LDS ordering)
  f32x4 acc2[2][2] = {};
  #pragma unroll
  for (int kk = 0; kk < 64; kk += 32) {
    u16x8 ah[2], al[2];
    #pragma unroll
    for (int rt = 0; rt < 2; ++rt)
      split8(&H1[wave * 32 + rt * 16 + l15][kk + g * 8], ah[rt], al[rt]);
    #pragma unroll
    for (int ct = 0; ct < 2; ++ct) {
      u16x8 wh = *reinterpret_cast<const u16x8*>(&WT2h[ct * 16 + l15][kk + g * 8]);
      u16x8 wl = *reinterpret_cast<const u16x8*>(&WT2l[ct * 16 + l15][kk + g * 8]);
      #pragma unroll
      for (int rt = 0; rt < 2; ++rt) {
        acc2[rt][ct] = mfma16(ah[rt], wh, acc2[rt][ct]);
        acc2[rt][ct] = mfma16(al[rt], wh, acc2[rt][ct]);
        acc2[rt][ct] = mfma16(ah[rt], wl, acc2[rt][ct]);
      }
    }
  }
  #pragma unroll
  for (int ct = 0; ct < 2; ++ct) {
    float bv = B2[ct * 16 + l15];
    #pragma unroll
    for (int rt = 0; rt < 2; ++rt)
      #pragma unroll
      for (int r = 0; r < 4; ++r)
        bb[((size_t)br * 32768 + row0 + rt * 16 + g * 4 + r) * 64 + ct * 16 + l15] =
            fmaxf(acc2[rt][ct][r] + bv, 0.f);
  }
}

// ---------- x0 = relu(bb) -> split transposed store XT_hi/XT_lo (bf16) ----------
__global__ __launch_bounds__(256) void k_relu_t(const float* __restrict__ bb,
                                                unsigned short* __restrict__ XTh,
                                                unsigned short* __restrict__ XTl) {
  int bid = blockIdx.x;                       // 2*64*8
  int br = bid >> 9, rem = bid & 511, b = rem >> 3, tile = rem & 7;
  int n0 = tile * 64;
  __shared__ unsigned short xh[64][65], xl[64][65];
  const f32x4* src =
      reinterpret_cast<const f32x4*>(bb + ((size_t)(br * 64 + b) * 512 + n0) * 64);
  #pragma unroll
  for (int i = 0; i < 4; ++i) {
    int f = i * 256 + threadIdx.x;
    f32x4 v = src[f];
    int n = f >> 4, c4 = (f & 15) * 4;
    #pragma unroll
    for (int j = 0; j < 4; ++j) {
      float val = fmaxf(v[j], 0.f);
      unsigned short hb = f2bf(val);
      xh[n][c4 + j] = hb;
      xl[n][c4 + j] = f2bf(val - bf2f(hb));
    }
  }
  __syncthreads();
  int c = threadIdx.x >> 2, j0 = (threadIdx.x & 3) * 16;
  size_t base = ((size_t)(br * 64 + b) * 64 + c) * 512 + n0 + j0;
  u16x8 o0, o1, p0, p1;
  #pragma unroll
  for (int i = 0; i < 8; ++i) {
    o0[i] = xh[j0 + i][c]; o1[i] = xh[j0 + 8 + i][c];
    p0[i] = xl[j0 + i][c]; p1[i] = xl[j0 + 8 + i][c];
  }
  *reinterpret_cast<u16x8*>(XTh + base) = o0;
  *reinterpret_cast<u16x8*>(XTh + base + 8) = o1;
  *reinterpret_cast<u16x8*>(XTl + base) = p0;
  *reinterpret_cast<u16x8*>(XTl + base + 8) = p1;
}

// ---------- fused iteration: t = adj@x ; 2 MLP layers ; tanh(bb + .) ----------
// 256 blocks: rb*128 + br*64 + b (rb∈{0,1}; sharers 128 apart -> same XCD L2).
// 64 rows/wave (r14-proven: reuse beats occupancy). AIN8=0: bf16 hi/lo input
// (iter 0). AIN8=1: two i8 digit planes (x = qh/127 + ql/127^2), adjacency
// via mfma_i32 16x16x64 (exact i32 accum).
template <int AIN8, int LAST>
__global__ __launch_bounds__(256, 2) void k_iter(
    const unsigned* __restrict__ bits,
    const unsigned short* __restrict__ XTbfh, const unsigned short* __restrict__ XTbfl,
    const char* __restrict__ X8h_in, const char* __restrict__ X8l_in,
    const float* __restrict__ bb,
    const float* __restrict__ we_w, const float* __restrict__ we_b,
    char* __restrict__ X8h_out, char* __restrict__ X8l_out,
    float* __restrict__ Spart) {
  int bid = blockIdx.x;                       // 2rb * 2br * 64b = 256
  int rb = bid >> 7, br = (bid >> 6) & 1, b = bid & 63;
  int n0 = rb * 256;
  __shared__ __attribute__((aligned(16))) unsigned short WT0h[64][72];
  __shared__ __attribute__((aligned(16))) unsigned short WT0l[64][72];
  __shared__ __attribute__((aligned(16))) unsigned short WT1h[64][72];
  __shared__ __attribute__((aligned(16))) unsigned short WT1l[64][72];
  __shared__ __attribute__((aligned(16))) char uni[34816];  // ts | xh8+xl8
  __shared__ float colsum[16][64];
  auto ts  = reinterpret_cast<float(*)[32][68]>(uni);       // [4][32][68]
  auto xh8 = reinterpret_cast<char(*)[65]>(uni);            // [128][65]
  auto xl8 = reinterpret_cast<char(*)[65]>(uni + 8320);     // [128][65]

  for (int idx = threadIdx.x; idx < 4096; idx += 256) {
    int k = idx >> 6, c = idx & 63;
    float w0 = we_w[k * 64 + c], w1 = we_w[4096 + k * 64 + c];
    unsigned short h0 = f2bf(w0), h1b = f2bf(w1);
    WT0h[c][k] = h0; WT0l[c][k] = f2bf(w0 - bf2f(h0));
    WT1h[c][k] = h1b; WT1l[c][k] = f2bf(w1 - bf2f(h1b));
  }
  __syncthreads();

  int wave = threadIdx.x >> 6, lane = threadIdx.x & 63;
  int l15 = lane & 15, g = lane >> 4;
  int rowbase = n0 + wave * 64;

  // ---- adjacency bits for 4 row-tiles ----
  union BWU { uint4 v[4]; unsigned w[16]; };
  BWU bw0, bw1, bw2, bw3;
  {
    const unsigned* p0 =
        bits + (size_t)br * 524288 + ((size_t)b * 512 + rowbase + l15) * 16;
    #pragma unroll
    for (int q = 0; q < 4; ++q) {
      bw0.v[q] = reinterpret_cast<const uint4*>(p0)[q];
      bw1.v[q] = reinterpret_cast<const uint4*>(p0 + 256)[q];
      bw2.v[q] = reinterpret_cast<const uint4*>(p0 + 512)[q];
      bw3.v[q] = reinterpret_cast<const uint4*>(p0 + 768)[q];
    }
  }

  float tv[4][4][4];   // t values, [row-tile][ct][r]

  if constexpr (!AIN8) {
    size_t xtbase = (size_t)(br * 64 + b) * 64 * 512;
    f32x4 acc[4][4] = {};
    #pragma unroll
    for (int kk = 0; kk < 512; kk += 32) {
      u16x8 a0, a1, a2, a3;
      {
        unsigned w0 = bw0.w[kk >> 5] >> (g * 8), w1 = bw1.w[kk >> 5] >> (g * 8);
        unsigned w2 = bw2.w[kk >> 5] >> (g * 8), w3 = bw3.w[kk >> 5] >> (g * 8);
        union { unsigned u[4]; u16x8 v; } r0, r1, r2, r3;
        #pragma unroll
        for (int i = 0; i < 4; ++i) {
          r0.u[i] = (((w0 >> (2 * i)) & 1u) ? 0x3F80u : 0u) |
                    (((w0 >> (2 * i + 1)) & 1u) ? 0x3F800000u : 0u);
          r1.u[i] = (((w1 >> (2 * i)) & 1u) ? 0x3F80u : 0u) |
                    (((w1 >> (2 * i + 1)) & 1u) ? 0x3F800000u : 0u);
          r2.u[i] = (((w2 >> (2 * i)) & 1u) ? 0x3F80u : 0u) |
                    (((w2 >> (2 * i + 1)) & 1u) ? 0x3F800000u : 0u);
          r3.u[i] = (((w3 >> (2 * i)) & 1u) ? 0x3F80u : 0u) |
                    (((w3 >> (2 * i + 1)) & 1u) ? 0x3F800000u : 0u);
        }
        a0 = r0.v; a1 = r1.v; a2 = r2.v; a3 = r3.v;
      }
      #pragma unroll
      for (int ct = 0; ct < 4; ++ct) {
        size_t off = xtbase + (size_t)(ct * 16 + l15) * 512 + kk + g * 8;
        u16x8 bh = *reinterpret_cast<const u16x8*>(XTbfh + off);
        u16x8 bl = *reinterpret_cast<const u16x8*>(XTbfl + off);
        acc[0][ct] = mfma16(a0, bh, acc[0][ct]);
        acc[0][ct] = mfma16(a0, bl, acc[0][ct]);
        acc[1][ct] = mfma16(a1, bh, acc[1][ct]);
        acc[1][ct] = mfma16(a1, bl, acc[1][ct]);
        acc[2][ct] = mfma16(a2, bh, acc[2][ct]);
        acc[2][ct] = mfma16(a2, bl, acc[2][ct]);
        acc[3][ct] = mfma16(a3, bh, acc[3][ct]);
        acc[3][ct] = mfma16(a3, bl, acc[3][ct]);
      }
    }
    #pragma unroll
    for (int rt = 0; rt < 4; ++rt)
      #pragma unroll
      for (int ct = 0; ct < 4; ++ct)
        #pragma unroll
        for (int r = 0; r < 4; ++r)
          tv[rt][ct][r] = acc[rt][ct][r];
  } else {
    size_t x8base = (size_t)(br * 64 + b) * 64 * 512;
    i32x4 acch[4][4] = {};
    i32x4 accl[4][4] = {};
    #pragma unroll
    for (int c64 = 0; c64 < 8; ++c64) {
      int kk = c64 * 64;
      int wi = (kk >> 5) + (g >> 1), shv = (g & 1) * 16;
      uint4 a0 = expand16((bw0.w[wi] >> shv) & 0xFFFFu);
      uint4 a1 = expand16((bw1.w[wi] >> shv) & 0xFFFFu);
      uint4 a2 = expand16((bw2.w[wi] >> shv) & 0xFFFFu);
      uint4 a3 = expand16((bw3.w[wi] >> shv) & 0xFFFFu);
      #pragma unroll
      for (int ct = 0; ct < 4; ++ct) {
        size_t off = x8base + (size_t)(ct * 16 + l15) * 512 + kk + g * 16;
        uint4 bh = *reinterpret_cast<const uint4*>(X8h_in + off);
        uint4 bl = *reinterpret_cast<const uint4*>(X8l_in + off);
        acch[0][ct] = mfma8(a0, bh, acch[0][ct]);
        accl[0][ct] = mfma8(a0, bl, accl[0][ct]);
        acch[1][ct] = mfma8(a1, bh, acch[1][ct]);
        accl[1][ct] = mfma8(a1, bl, accl[1][ct]);
        acch[2][ct] = mfma8(a2, bh, acch[2][ct]);
        accl[2][ct] = mfma8(a2, bl, accl[2][ct]);
        acch[3][ct] = mfma8(a3, bh, acch[3][ct]);
        accl[3][ct] = mfma8(a3, bl, accl[3][ct]);
      }
    }
    #pragma unroll
    for (int rt = 0; rt < 4; ++rt)
      #pragma unroll
      for (int ct = 0; ct < 4; ++ct)
        #pragma unroll
        for (int r = 0; r < 4; ++r)
          tv[rt][ct][r] = (float)acch[rt][ct][r] * (1.f / 127.f) +
                          (float)accl[rt][ct][r] * (1.f / 16129.f);
  }

  float sacc[4] = {0.f, 0.f, 0.f, 0.f};

  #pragma unroll
  for (int p = 0; p < 2; ++p) {
    if (!LAST && p) __syncthreads();   // prev pass's store read xh8 before ts reuse

    // stage t rows (pass p covers row-tiles 2p, 2p+1); wave-local ordering
    #pragma unroll
    for (int rt = 0; rt < 2; ++rt)
      #pragma unroll
      for (int ct = 0; ct < 4; ++ct)
        #pragma unroll
        for (int r = 0; r < 4; ++r)
          ts[wave][rt * 16 + g * 4 + r][ct * 16 + l15] = tv[2 * p + rt][ct][r];

    // ---- embed layer 1 ----
    f32x4 acc1[2][4] = {};
    #pragma unroll
    for (int kk = 0; kk < 64; kk += 32) {
      u16x8 ah[2], al[2];
      #pragma unroll
      for (int rt = 0; rt < 2; ++rt)
        split8(&ts[wave][rt * 16 + l15][kk + g * 8], ah[rt], al[rt]);
      #pragma unroll
      for (int ct = 0; ct < 4; ++ct) {
        u16x8 wh = *reinterpret_cast<const u16x8*>(&WT0h[ct * 16 + l15][kk + g * 8]);
        u16x8 wl = *reinterpret_cast<const u16x8*>(&WT0l[ct * 16 + l15][kk + g * 8]);
        #pragma unroll
        for (int rt = 0; rt < 2; ++rt) {
          acc1[rt][ct] = mfma16(ah[rt], wh, acc1[rt][ct]);
          acc1[rt][ct] = mfma16(al[rt], wh, acc1[rt][ct]);
          acc1[rt][ct] = mfma16(ah[rt], wl, acc1[rt][ct]);
        }
      }
    }
    #pragma unroll
    for (int rt = 0; rt < 2; ++rt)
      #pragma unroll
      for (int ct = 0; ct < 4; ++ct) {
        float bv = we_b[ct * 16 + l15];
        #pragma unroll
        for (int r = 0; r < 4; ++r)
          ts[wave][rt * 16 + g * 4 + r][ct * 16 + l15] =
              fmaxf(acc1[rt][ct][r] + bv, 0.f);
      }

    // ---- embed layer 2 ----
    f32x4 acc2[2][4] = {};
    #pragma unroll
    for (int kk = 0; kk < 64; kk += 32) {
      u16x8 ah[2], al[2];
      #pragma unroll
      for (int rt = 0; rt < 2; ++rt)
        split8(&ts[wave][rt * 16 + l15][kk + g * 8], ah[rt], al[rt]);
      #pragma unroll
      for (int ct = 0; ct < 4; ++ct) {
        u16x8 wh = *reinterpret_cast<const u16x8*>(&WT1h[ct * 16 + l15][kk + g * 8]);
        u16x8 wl = *reinterpret_cast<const u16x8*>(&WT1l[ct * 16 + l15][kk + g * 8]);
        #pragma unroll
        for (int rt = 0; rt < 2; ++rt) {
          acc2[rt][ct] = mfma16(ah[rt], wh, acc2[rt][ct]);
          acc2[rt][ct] = mfma16(al[rt], wh, acc2[rt][ct]);
          acc2[rt][ct] = mfma16(ah[rt], wl, acc2[rt][ct]);
        }
      }
    }

    const float* bbrow =
        bb + ((size_t)(br * 64 + b) * 512 + rowbase + p * 32) * 64;

    if (!LAST) {
      __syncthreads();   // all waves done with ts before xh8/xl8 alias reuse
      #pragma unroll
      for (int rt = 0; rt < 2; ++rt)
        #pragma unroll
        for (int ct = 0; ct < 4; ++ct) {
          float bv = we_b[64 + ct * 16 + l15];
          #pragma unroll
          for (int r = 0; r < 4; ++r) {
            int rr = rt * 16 + g * 4 + r, cc = ct * 16 + l15;
            float t3 = fmaxf(acc2[rt][ct][r] + bv, 0.f);
            float v = tanh_fast(bbrow[rr * 64 + cc] + t3);
            float s = v * 127.f;
            float qhf = rintf(s);
            float qlf = rintf((s - qhf) * 127.f);
            xh8[wave * 32 + rr][cc] = (char)(int)qhf;
            xl8[wave * 32 + rr][cc] = (char)(int)qlf;
          }
        }
      __syncthreads();
      // transpose store: thread (c, w4) stores 32 n-bytes for column c
      int c = threadIdx.x >> 2, w4 = threadIdx.x & 3;
      int j0 = w4 * 32;
      size_t base = ((size_t)(br * 64 + b) * 64 + c) * 512 + n0 + w4 * 64 + p * 32;
      union { uint4 v[2]; char bch[32]; } oh, ol;
      #pragma unroll
      for (int i = 0; i < 32; ++i) {
        oh.bch[i] = xh8[j0 + i][c];
        ol.bch[i] = xl8[j0 + i][c];
      }
      *reinterpret_cast<uint4*>(X8h_out + base) = oh.v[0];
      *reinterpret_cast<uint4*>(X8h_out + base + 16) = oh.v[1];
      *reinterpret_cast<uint4*>(X8l_out + base) = ol.v[0];
      *reinterpret_cast<uint4*>(X8l_out + base + 16) = ol.v[1];
    } else {
      #pragma unroll
      for (int ct = 0; ct < 4; ++ct) {
        float bv = we_b[64 + ct * 16 + l15];
        float s = 0.f;
        #pragma unroll
        for (int rt = 0; rt < 2; ++rt)
          #pragma unroll
          for (int r = 0; r < 4; ++r) {
            int rr = rt * 16 + g * 4 + r, cc = ct * 16 + l15;
            float t3 = fmaxf(acc2[rt][ct][r] + bv, 0.f);
            s += tanh_fast(bbrow[rr * 64 + cc] + t3);
          }
        sacc[ct] += s;
      }
    }
  }

  if (LAST) {
    #pragma unroll
    for (int ct = 0; ct < 4; ++ct)
      colsum[wave * 4 + g][ct * 16 + l15] = sacc[ct];
    __syncthreads();
    if (threadIdx.x < 64) {
      float s = 0.f;
      #pragma unroll
      for (int q = 0; q < 16; ++q) s += colsum[q][threadIdx.x];
      Spart[((size_t)(br * 64 + b) * 2 + rb) * 64 + threadIdx.x] = s;
    }
  }
}

// ---------- final: e = S@wout + bout ; cosine ----------
__global__ __launch_bounds__(64) void k_final(const float* __restrict__ Spart,
                                              const float* __restrict__ wout,
                                              const float* __restrict__ bout,
                                              float* __restrict__ out) {
  int b = blockIdx.x, c = threadIdx.x;
  __shared__ float s1s[64], s2s[64];
  float s1 = 0.f, s2 = 0.f;
  #pragma unroll
  for (int tl = 0; tl < 2; ++tl) {
    s1 += Spart[((size_t)(0 * 64 + b) * 2 + tl) * 64 + c];
    s2 += Spart[((size_t)(1 * 64 + b) * 2 + tl) * 64 + c];
  }
  s1s[c] = s1; s2s[c] = s2;
  __syncthreads();
  float e1 = bout[c], e2 = bout[c];
  for (int k = 0; k < 64; ++k) {
    float w = wout[k * 64 + c];
    e1 += s1s[k] * w;
    e2 += s2s[k] * w;
  }
  float nm = e1 * e2, dA = e1 * e1, dB = e2 * e2;
  #pragma unroll
  for (int off = 32; off; off >>= 1) {
    nm += __shfl_xor(nm, off);
    dA += __shfl_xor(dA, off);
    dB += __shfl_xor(dB, off);
  }
  if (c == 0) out[b] = nm / sqrtf(dA * dB + 1e-10f);
}

// ---------- launch ----------
extern "C" void kernel_launch(void* const* d_in, const int* in_sizes, int n_in,
                              void* d_out, int out_size, void* d_ws, size_t ws_size,
                              hipStream_t stream) {
  const int*   cfg1 = (const int*)d_in[0];
  const float* lit1 = (const float*)d_in[2];
  const float* sem1 = (const float*)d_in[3];
  const int*   cfg2 = (const int*)d_in[4];
  const float* lit2 = (const float*)d_in[6];
  const float* sem2 = (const float*)d_in[7];
  const float* d1w1 = (const float*)d_in[8];
  const float* d1b1 = (const float*)d_in[9];
  const float* d2w1 = (const float*)d_in[10];
  const float* d2b1 = (const float*)d_in[11];
  const float* lk1  = (const float*)d_in[12];
  const float* lrk1 = (const float*)d_in[13];
  const float* lb1  = (const float*)d_in[14];
  const float* d1w2 = (const float*)d_in[15];
  const float* d1b2 = (const float*)d_in[16];
  const float* d2w2 = (const float*)d_in[17];
  const float* d2b2 = (const float*)d_in[18];
  const float* lk2  = (const float*)d_in[19];
  const float* lrk2 = (const float*)d_in[20];
  const float* lb2  = (const float*)d_in[21];
  const float* we_w = (const float*)d_in[22];
  const float* we_b = (const float*)d_in[23];
  const float* wout = (const float*)d_in[24];
  const float* bout = (const float*)d_in[25];

  char* ws = (char*)d_ws;
  float* bb   = (float*)ws;                               // [2][32768][64]  0 .. 16.78M
  float* xk   = (float*)(ws + 16777216);                  // [2][32768][128] 16.78 .. 50.33M
  // post-LSTM aliases into dead xk:
  unsigned short* XTbfh = (unsigned short*)(ws + 16777216); // bf16 x0 hi, 8.39M
  unsigned short* XTbfl = (unsigned short*)(ws + 25165824); // bf16 x0 lo, 8.39M
  char* A8h = ws + 33554432;                              // i8 planes, 4.19M each
  char* A8l = ws + 37748736;
  char* B8h = ws + 41943040;
  char* B8l = ws + 46137344;                              // .. 50.33M
  float* Spart = (float*)(ws + 58720256);                 // 64 KB
  unsigned* bits = (unsigned*)(ws + 58982400);            // 4.19 MB

  // sem -> xk (must precede front; LSTM reads xk)
  k_ff<64, 128, 0><<<512, 256, 0, stream>>>(sem1, sem2, lk1, lk2, lb1, lb2,
                                            xk, 128, 4194304L);

  // LSTM (critical path) ∥ pack ∥ lit-MLP — separate block ranges
  k_front<<<784, 256, 0, stream>>>(xk, lrk1, lrk2, bb, cfg1, cfg2, bits,
                                   lit1, lit2, d1w1, d1w2, d1b1, d1b2,
                                   d2w1, d2w2, d2b1, d2b2);

  k_relu_t<<<1024, 256, 0, stream>>>(bb, XTbfh, XTbfl);   // xk now dead

  // it0: bf16 in -> i8 out ; it1-3: i8 ping-pong ; it4: i8 in, colsums
  k_iter<0, 0><<<256, 256, 0, stream>>>(bits, XTbfh, XTbfl, nullptr, nullptr,
                                        bb, we_w, we_b, A8h, A8l, Spart);
  k_iter<1, 0><<<256, 256, 0, stream>>>(bits, nullptr, nullptr, A8h, A8l,
                                        bb, we_w, we_b, B8h, B8l, Spart);
  k_iter<1, 0><<<256, 256, 0, stream>>>(bits, nullptr, nullptr, B8h, B8l,
                                        bb, we_w, we_b, A8h, A8l, Spart);
  k_iter<1, 0><<<256, 256, 0, stream>>>(bits, nullptr, nullptr, A8h, A8l,
                                        bb, we_w, we_b, B8h, B8l, Spart);
  k_iter<1, 1><<<256, 256, 0, stream>>>(bits, nullptr, nullptr, B8h, B8l,
                                        bb, we_w, we_b, A8h, A8l, Spart);

  k_final<<<64, 64, 0, stream>>>(Spart, wout, bout, (float*)d_out);
}

// Round 17
// 308.436 us; speedup vs baseline: 1.0618x; 1.0618x over previous
//
#include <hip/hip_runtime.h>

#define DEV static __device__ __forceinline__

typedef float  f32x2 __attribute__((ext_vector_type(2)));
typedef float  f32x4 __attribute__((ext_vector_type(4)));
typedef float  f32x8 __attribute__((ext_vector_type(8)));
typedef __bf16 bf16x8 __attribute__((ext_vector_type(8)));
typedef unsigned short u16x8 __attribute__((ext_vector_type(8)));
typedef int    i32x4 __attribute__((ext_vector_type(4)));

// ---------- helpers ----------
DEV unsigned short f2bf(float f) {              // RNE f32 -> bf16 bits
  unsigned u = __builtin_bit_cast(unsigned, f);
  u += 0x7FFFu + ((u >> 16) & 1u);
  return (unsigned short)(u >> 16);
}
DEV float bf2f(unsigned short h) {
  unsigned u = (unsigned)h << 16;
  return __builtin_bit_cast(float, u);
}

DEV f32x4 mfma16(u16x8 a, u16x8 b, f32x4 c) {
  return __builtin_amdgcn_mfma_f32_16x16x32_bf16(
      __builtin_bit_cast(bf16x8, a), __builtin_bit_cast(bf16x8, b), c, 0, 0, 0);
}
DEV i32x4 mfma8(uint4 a, uint4 b, i32x4 c) {    // i8 16x16x64
  return __builtin_amdgcn_mfma_i32_16x16x64_i8(
      __builtin_bit_cast(i32x4, a), __builtin_bit_cast(i32x4, b), c, 0, 0, 0);
}

// raw hardware exp2 (v_exp_f32: D = 2^S0)
DEV float exp2_hw(float x) { float r; asm("v_exp_f32 %0, %1" : "=v"(r) : "v"(x)); return r; }
DEV float sig_fast(float x) { return __builtin_amdgcn_rcpf(1.f + exp2_hw(-1.44269504f * x)); }
DEV float tanh_fast(float x) { return 1.f - 2.f * __builtin_amdgcn_rcpf(exp2_hw(2.88539008f * x) + 1.f); }

// packed dual-FMA: acc.{x,y} += a.{x,y} * b.{x,y}
DEV void pkfma(f32x2& acc, f32x2 a, f32x2 b) {
  asm("v_pk_fma_f32 %0, %1, %2, %0" : "+v"(acc) : "v"(a), "v"(b));
}

// 16 bits -> 16 bytes {0,1} (byte i = bit i): nibble-multiply spread
DEV uint4 expand16(unsigned hw) {
  uint4 r;
  r.x = ((hw         & 0xFu) * 0x00204081u) & 0x01010101u;
  r.y = (((hw >> 4)  & 0xFu) * 0x00204081u) & 0x01010101u;
  r.z = (((hw >> 8)  & 0xFu) * 0x00204081u) & 0x01010101u;
  r.w = (((hw >> 12) & 0xFu) * 0x00204081u) & 0x01010101u;
  return r;
}

// split 8 f32 -> hi/lo bf16 fragments (v = hi + lo exactly to ~2^-17)
DEV void split8(const float* p, u16x8& h, u16x8& l) {
  union { f32x4 q[2]; f32x8 o; } u;
  u.q[0] = *reinterpret_cast<const f32x4*>(p);
  u.q[1] = *reinterpret_cast<const f32x4*>(p + 4);
  #pragma unroll
  for (int i = 0; i < 8; ++i) {
    float v = u.o[i];
    unsigned short hb = f2bf(v);
    h[i] = hb;
    l[i] = f2bf(v - bf2f(hb));
  }
}

// ---------- split-precision GEMM: C = act(A[32768,K] @ W[K,NC] + b) ----------
template <int K, int NC, int ACT>
__global__ __launch_bounds__(256) void k_ff(
    const float* __restrict__ A1, const float* __restrict__ A2,
    const float* __restrict__ W1, const float* __restrict__ W2,
    const float* __restrict__ b1, const float* __restrict__ b2,
    float* __restrict__ C, int ldC, long brCstride) {
  int bid = blockIdx.x;
  int br = bid >> 8, rbk = bid & 255;
  const float* A = br ? A2 : A1;
  const float* W = br ? W2 : W1;
  const float* bias = br ? b2 : b1;

  __shared__ __attribute__((aligned(16))) unsigned short WTh[NC][K + 8];
  __shared__ __attribute__((aligned(16))) unsigned short WTl[NC][K + 8];
  for (int idx = threadIdx.x; idx < K * NC; idx += 256) {
    int k = idx / NC, c = idx % NC;
    float w = W[idx];
    unsigned short hb = f2bf(w);
    WTh[c][k] = hb;
    WTl[c][k] = f2bf(w - bf2f(hb));
  }
  __syncthreads();

  int wave = threadIdx.x >> 6, lane = threadIdx.x & 63;
  int l15 = lane & 15, g = lane >> 4;
  int row0 = rbk * 128 + wave * 32;

  f32x4 acc[2][NC / 16] = {};
  for (int kk = 0; kk < K; kk += 32) {
    u16x8 ah[2], al[2];
    #pragma unroll
    for (int rt = 0; rt < 2; ++rt)
      split8(A + (size_t)(row0 + rt * 16 + l15) * K + kk + g * 8, ah[rt], al[rt]);
    #pragma unroll
    for (int ct = 0; ct < NC / 16; ++ct) {
      u16x8 wh = *reinterpret_cast<const u16x8*>(&WTh[ct * 16 + l15][kk + g * 8]);
      u16x8 wl = *reinterpret_cast<const u16x8*>(&WTl[ct * 16 + l15][kk + g * 8]);
      #pragma unroll
      for (int rt = 0; rt < 2; ++rt) {
        acc[rt][ct] = mfma16(ah[rt], wh, acc[rt][ct]);
        acc[rt][ct] = mfma16(al[rt], wh, acc[rt][ct]);
        acc[rt][ct] = mfma16(ah[rt], wl, acc[rt][ct]);
      }
    }
  }

  float bv[NC / 16];
  #pragma unroll
  for (int ct = 0; ct < NC / 16; ++ct) bv[ct] = bias[ct * 16 + l15];
  #pragma unroll
  for (int rt = 0; rt < 2; ++rt)
    #pragma unroll
    for (int ct = 0; ct < NC / 16; ++ct)
      #pragma unroll
      for (int r = 0; r < 4; ++r) {
        float v = acc[rt][ct][r] + bv[ct];
        if (ACT) v = fmaxf(v, 0.f);
        C[(size_t)br * brCstride +
          (size_t)(row0 + rt * 16 + g * 4 + r) * ldC + ct * 16 + l15] = v;
      }
}

// ---------- FRONT: blocks 0..31   = LSTM (4 indep waves, one (br,b) each)
//                   blocks 32..287 = pack cfg->bits
//                   blocks 288..799= fused lit-MLP
// LDS padded past 80KB -> 1 block/CU: LSTM CUs isolated from pack/MLP
// contention (r13/r14: isolation recovered ~32us on the chain). ----------
__global__ __launch_bounds__(256) void k_front(
    const float* __restrict__ xk,
    const float* __restrict__ lrk1, const float* __restrict__ lrk2,
    float* __restrict__ bb,
    const int* __restrict__ cfg1, const int* __restrict__ cfg2,
    unsigned* __restrict__ bits,
    const float* __restrict__ lit1, const float* __restrict__ lit2,
    const float* __restrict__ d1w1, const float* __restrict__ d1w2,
    const float* __restrict__ d1b1, const float* __restrict__ d1b2,
    const float* __restrict__ d2w1, const float* __restrict__ d2w2,
    const float* __restrict__ d2b1, const float* __restrict__ d2b2) {
  __shared__ __attribute__((aligned(16))) unsigned short WT1h[64][136];
  __shared__ __attribute__((aligned(16))) unsigned short WT1l[64][136];
  __shared__ __attribute__((aligned(16))) unsigned short WT2h[32][72];
  __shared__ __attribute__((aligned(16))) unsigned short WT2l[32][72];
  __shared__ __attribute__((aligned(16))) float H1[128][68];
  __shared__ __attribute__((aligned(16))) float sh[4][64];
  __shared__ __attribute__((aligned(16))) float lds_pad[520];  // -> 81952B, 1 blk/CU

  int bid = blockIdx.x;
  int wave = threadIdx.x >> 6, lane = threadIdx.x & 63;
  if (bid == 0x3FFFFFFF) ((volatile float*)lds_pad)[threadIdx.x & 511] = 1.f;

  if (bid < 32) {
    // ---- LSTM recurrence: one (br,b) per wave; wave-private LDS, no barriers ----
    int gb = bid * 4 + wave;                  // 0..127
    int br = gb >> 6, b = gb & 63;
    int u = lane & 31, hi = lane >> 5;
    int c0 = u + (hi << 5), c1 = c0 + 64;     // lo: i,g ; hi: f,o
    const float* rkp = br ? lrk2 : lrk1;
    f32x2 rk0p[16], rk1p[16];
    #pragma unroll
    for (int k2 = 0; k2 < 16; ++k2) {
      rk0p[k2] = f32x2{rkp[(2 * k2) * 128 + c0], rkp[(2 * k2 + 1) * 128 + c0]};
      rk1p[k2] = f32x2{rkp[(2 * k2) * 128 + c1], rkp[(2 * k2 + 1) * 128 + c1]};
    }
    float* shw = &sh[wave][0];
    shw[lane] = 0.f;

    const float* xkb = xk + ((size_t)br * 32768 + (size_t)b * 512) * 128;
    float* bbo = bb + ((size_t)br * 32768 + (size_t)b * 512) * 64 + 32;
    float cst = 0.f;

    // 8-deep prefetch; reads past t=511 (to t=519) land in mapped ws -> safe
    float z00 = xkb[0 * 128 + c0], z10 = xkb[0 * 128 + c1];
    float z01 = xkb[1 * 128 + c0], z11 = xkb[1 * 128 + c1];
    float z02 = xkb[2 * 128 + c0], z12 = xkb[2 * 128 + c1];
    float z03 = xkb[3 * 128 + c0], z13 = xkb[3 * 128 + c1];
    float z04 = xkb[4 * 128 + c0], z14 = xkb[4 * 128 + c1];
    float z05 = xkb[5 * 128 + c0], z15 = xkb[5 * 128 + c1];
    float z06 = xkb[6 * 128 + c0], z16 = xkb[6 * 128 + c1];
    float z07 = xkb[7 * 128 + c0], z17 = xkb[7 * 128 + c1];

    union Q { f32x4 q; f32x2 p[2]; };

#define LSTM_STEP(T, ZA, ZB) {                                          \
    float a0 = ZA, a1 = ZB;                                             \
    ZA = xkb[((T) + 8) * 128 + c0]; ZB = xkb[((T) + 8) * 128 + c1];     \
    Q q0, q1, q2, q3, q4, q5, q6, q7;                                   \
    q0.q = *reinterpret_cast<const f32x4*>(&shw[32]);                   \
    q1.q = *reinterpret_cast<const f32x4*>(&shw[36]);                   \
    q2.q = *reinterpret_cast<const f32x4*>(&shw[40]);                   \
    q3.q = *reinterpret_cast<const f32x4*>(&shw[44]);                   \
    q4.q = *reinterpret_cast<const f32x4*>(&shw[48]);                   \
    q5.q = *reinterpret_cast<const f32x4*>(&shw[52]);                   \
    q6.q = *reinterpret_cast<const f32x4*>(&shw[56]);                   \
    q7.q = *reinterpret_cast<const f32x4*>(&shw[60]);                   \
    f32x2 A0 = {0.f, 0.f}, A1 = {0.f, 0.f};                             \
    f32x2 B0 = {0.f, 0.f}, B1 = {0.f, 0.f};                             \
    pkfma(A0, q0.p[0], rk0p[0]);  pkfma(B0, q0.p[0], rk1p[0]);          \
    pkfma(A1, q0.p[1], rk0p[1]);  pkfma(B1, q0.p[1], rk1p[1]);          \
    pkfma(A0, q1.p[0], rk0p[2]);  pkfma(B0, q1.p[0], rk1p[2]);          \
    pkfma(A1, q1.p[1], rk0p[3]);  pkfma(B1, q1.p[1], rk1p[3]);          \
    pkfma(A0, q2.p[0], rk0p[4]);  pkfma(B0, q2.p[0], rk1p[4]);          \
    pkfma(A1, q2.p[1], rk0p[5]);  pkfma(B1, q2.p[1], rk1p[5]);          \
    pkfma(A0, q3.p[0], rk0p[6]);  pkfma(B0, q3.p[0], rk1p[6]);          \
    pkfma(A1, q3.p[1], rk0p[7]);  pkfma(B1, q3.p[1], rk1p[7]);          \
    pkfma(A0, q4.p[0], rk0p[8]);  pkfma(B0, q4.p[0], rk1p[8]);          \
    pkfma(A1, q4.p[1], rk0p[9]);  pkfma(B1, q4.p[1], rk1p[9]);          \
    pkfma(A0, q5.p[0], rk0p[10]); pkfma(B0, q5.p[0], rk1p[10]);         \
    pkfma(A1, q5.p[1], rk0p[11]); pkfma(B1, q5.p[1], rk1p[11]);         \
    pkfma(A0, q6.p[0], rk0p[12]); pkfma(B0, q6.p[0], rk1p[12]);         \
    pkfma(A1, q6.p[1], rk0p[13]); pkfma(B1, q6.p[1], rk1p[13]);         \
    pkfma(A0, q7.p[0], rk0p[14]); pkfma(B0, q7.p[0], rk1p[14]);         \
    pkfma(A1, q7.p[1], rk0p[15]); pkfma(B1, q7.p[1], rk1p[15]);         \
    float a0f = a0 + (A0.x + A1.x) + (A0.y + A1.y);                     \
    float a1f = a1 + (B0.x + B1.x) + (B0.y + B1.y);                     \
    float s0 = sig_fast(a0f);                  /* sig(i) | sig(f)  */   \
    float s1 = hi ? sig_fast(a1f) : tanh_fast(a1f); /* tanh(g)|sig(o)*/ \
    float at = s0 * s1;                        /* lo: sig(i)tanh(g)*/   \
    float rc = __shfl_xor(at, 32);                                      \
    cst = s0 * cst + rc;                       /* hi lanes valid   */   \
    float hv = s1 * tanh_fast(cst);                                     \
    shw[lane] = hv;                                                     \
    if (hi) bbo[(T) * 64 + u] = hv;                                     \
  }

    for (int tb = 0; tb < 512; tb += 8) {
      LSTM_STEP(tb + 0, z00, z10)
      LSTM_STEP(tb + 1, z01, z11)
      LSTM_STEP(tb + 2, z02, z12)
      LSTM_STEP(tb + 3, z03, z13)
      LSTM_STEP(tb + 4, z04, z14)
      LSTM_STEP(tb + 5, z05, z15)
      LSTM_STEP(tb + 6, z06, z16)
      LSTM_STEP(tb + 7, z07, z17)
    }
#undef LSTM_STEP
    return;
  }

  if (bid < 288) {
    // ---- pack: 65536 threads x 16 words, coalesced ----
    unsigned worker = (unsigned)(bid - 32) * 256u + threadIdx.x;
    #pragma unroll
    for (int j = 0; j < 16; ++j) {
      unsigned idx = worker + (unsigned)j * 65536u;   // 0 .. 1048575
      unsigned br2 = idx >> 19;
      unsigned rem = idx & 524287u;
      const int4* p = reinterpret_cast<const int4*>(br2 ? cfg2 : cfg1) + rem * 8;
      unsigned m = 0;
      #pragma unroll
      for (int q = 0; q < 8; ++q) {
        int4 v = p[q];
        unsigned base = q * 4;
        m |= ((unsigned)v.x & 1u) << (base + 0);
        m |= ((unsigned)v.y & 1u) << (base + 1);
        m |= ((unsigned)v.z & 1u) << (base + 2);
        m |= ((unsigned)v.w & 1u) << (base + 3);
      }
      bits[idx] = m;
    }
    return;
  }

  // ---- fused lit-MLP: 128 rows per block ----
  int bid2 = bid - 288;                       // 0..511
  int br = bid2 >> 8, rbk = bid2 & 255;
  const float* lit = br ? lit2 : lit1;
  const float* W1  = br ? d1w2 : d1w1;        // [128][64]
  const float* B1  = br ? d1b2 : d1b1;
  const float* W2  = br ? d2w2 : d2w1;        // [64][32]
  const float* B2  = br ? d2b2 : d2b1;

  for (int idx = threadIdx.x; idx < 8192; idx += 256) {
    int k = idx >> 6, c = idx & 63;
    float w = W1[idx];
    unsigned short hb = f2bf(w);
    WT1h[c][k] = hb;
    WT1l[c][k] = f2bf(w - bf2f(hb));
  }
  for (int idx = threadIdx.x; idx < 2048; idx += 256) {
    int k = idx >> 5, c = idx & 31;
    float w = W2[idx];
    unsigned short hb = f2bf(w);
    WT2h[c][k] = hb;
    WT2l[c][k] = f2bf(w - bf2f(hb));
  }
  __syncthreads();

  int l15 = lane & 15, g = lane >> 4;
  int row0 = rbk * 128 + wave * 32;

  f32x4 acc[2][4] = {};
  #pragma unroll
  for (int kk = 0; kk < 128; kk += 32) {
    u16x8 ah[2], al[2];
    #pragma unroll
    for (int rt = 0; rt < 2; ++rt)
      split8(lit + (size_t)(row0 + rt * 16 + l15) * 128 + kk + g * 8, ah[rt], al[rt]);
    #pragma unroll
    for (int ct = 0; ct < 4; ++ct) {
      u16x8 wh = *reinterpret_cast<const u16x8*>(&WT1h[ct * 16 + l15][kk + g * 8]);
      u16x8 wl = *reinterpret_cast<const u16x8*>(&WT1l[ct * 16 + l15][kk + g * 8]);
      #pragma unroll
      for (int rt = 0; rt < 2; ++rt) {
        acc[rt][ct] = mfma16(ah[rt], wh, acc[rt][ct]);
        acc[rt][ct] = mfma16(al[rt], wh, acc[rt][ct]);
        acc[rt][ct] = mfma16(ah[rt], wl, acc[rt][ct]);
      }
    }
  }
  #pragma unroll
  for (int ct = 0; ct < 4; ++ct) {
    float bv = B1[ct * 16 + l15];
    #pragma unroll
    for (int rt = 0; rt < 2; ++rt)
      #pragma unroll
      for (int r = 0; r < 4; ++r)
        H1[wave * 32 + rt * 16 + g * 4 + r][ct * 16 + l15] =
            fmaxf(acc[rt][ct][r] + bv, 0.f);
  }
  // layer 2 (wave-local H1 rows; same-wave LDS ordering)
  f32x4 acc2[2][2] = {};
  #pragma unroll
  for (int kk = 0; kk < 64; kk += 32) {
    u16x8 ah[2], al[2];
    #pragma unroll
    for (int rt = 0; rt < 2; ++rt)
      split8(&H1[wave * 32 + rt * 16 + l15][kk + g * 8], ah[rt], al[rt]);
    #pragma unroll
    for (int ct = 0; ct < 2; ++ct) {
      u16x8 wh = *reinterpret_cast<const u16x8*>(&WT2h[ct * 16 + l15][kk + g * 8]);
      u16x8 wl = *reinterpret_cast<const u16x8*>(&WT2l[ct * 16 + l15][kk + g * 8]);
      #pragma unroll
      for (int rt = 0; rt < 2; ++rt) {
        acc2[rt][ct] = mfma16(ah[rt], wh, acc2[rt][ct]);
        acc2[rt][ct] = mfma16(al[rt], wh, acc2[rt][ct]);
        acc2[rt][ct] = mfma16(ah[rt], wl, acc2[rt][ct]);
      }
    }
  }
  #pragma unroll
  for (int ct = 0; ct < 2; ++ct) {
    float bv = B2[ct * 16 + l15];
    #pragma unroll
    for (int rt = 0; rt < 2; ++rt)
      #pragma unroll
      for (int r = 0; r < 4; ++r)
        bb[((size_t)br * 32768 + row0 + rt * 16 + g * 4 + r) * 64 + ct * 16 + l15] =
            fmaxf(acc2[rt][ct][r] + bv, 0.f);
  }
}

// ---------- x0 = relu(bb) -> split transposed store XT_hi/XT_lo (bf16) ----------
__global__ __launch_bounds__(256) void k_relu_t(const float* __restrict__ bb,
                                                unsigned short* __restrict__ XTh,
                                                unsigned short* __restrict__ XTl) {
  int bid = blockIdx.x;                       // 2*64*8
  int br = bid >> 9, rem = bid & 511, b = rem >> 3, tile = rem & 7;
  int n0 = tile * 64;
  __shared__ unsigned short xh[64][65], xl[64][65];
  const f32x4* src =
      reinterpret_cast<const f32x4*>(bb + ((size_t)(br * 64 + b) * 512 + n0) * 64);
  #pragma unroll
  for (int i = 0; i < 4; ++i) {
    int f = i * 256 + threadIdx.x;
    f32x4 v = src[f];
    int n = f >> 4, c4 = (f & 15) * 4;
    #pragma unroll
    for (int j = 0; j < 4; ++j) {
      float val = fmaxf(v[j], 0.f);
      unsigned short hb = f2bf(val);
      xh[n][c4 + j] = hb;
      xl[n][c4 + j] = f2bf(val - bf2f(hb));
    }
  }
  __syncthreads();
  int c = threadIdx.x >> 2, j0 = (threadIdx.x & 3) * 16;
  size_t base = ((size_t)(br * 64 + b) * 64 + c) * 512 + n0 + j0;
  u16x8 o0, o1, p0, p1;
  #pragma unroll
  for (int i = 0; i < 8; ++i) {
    o0[i] = xh[j0 + i][c]; o1[i] = xh[j0 + 8 + i][c];
    p0[i] = xl[j0 + i][c]; p1[i] = xl[j0 + 8 + i][c];
  }
  *reinterpret_cast<u16x8*>(XTh + base) = o0;
  *reinterpret_cast<u16x8*>(XTh + base + 8) = o1;
  *reinterpret_cast<u16x8*>(XTl + base) = p0;
  *reinterpret_cast<u16x8*>(XTl + base + 8) = p1;
}

// ---------- fused iteration: t = adj@x ; 2 MLP layers ; tanh(bb + .) ----------
// 256 blocks: rb*128 + br*64 + b (rb∈{0,1}; sharers 128 apart -> same XCD L2).
// 64 rows/wave. AIN8=0: x input is bf16 hi/lo (iter 0). AIN8=1: x input is
// two i8 digit planes (x = qh/127 + ql/127^2), adjacency via mfma_i32 16x16x64.
template <int AIN8, int LAST>
__global__ __launch_bounds__(256, 2) void k_iter(
    const unsigned* __restrict__ bits,
    const unsigned short* __restrict__ XTbfh, const unsigned short* __restrict__ XTbfl,
    const char* __restrict__ X8h_in, const char* __restrict__ X8l_in,
    const float* __restrict__ bb,
    const float* __restrict__ we_w, const float* __restrict__ we_b,
    char* __restrict__ X8h_out, char* __restrict__ X8l_out,
    float* __restrict__ Spart) {
  int bid = blockIdx.x;                       // 2rb * 2br * 64b = 256
  int rb = bid >> 7, br = (bid >> 6) & 1, b = bid & 63;
  int n0 = rb * 256;
  __shared__ __attribute__((aligned(16))) unsigned short WT0h[64][72];
  __shared__ __attribute__((aligned(16))) unsigned short WT0l[64][72];
  __shared__ __attribute__((aligned(16))) unsigned short WT1h[64][72];
  __shared__ __attribute__((aligned(16))) unsigned short WT1l[64][72];
  __shared__ __attribute__((aligned(16))) char uni[34816];  // ts | xh8+xl8
  __shared__ float colsum[16][64];
  auto ts  = reinterpret_cast<float(*)[32][68]>(uni);       // [4][32][68]
  auto xh8 = reinterpret_cast<char(*)[65]>(uni);            // [128][65]
  auto xl8 = reinterpret_cast<char(*)[65]>(uni + 8320);     // [128][65]

  for (int idx = threadIdx.x; idx < 4096; idx += 256) {
    int k = idx >> 6, c = idx & 63;
    float w0 = we_w[k * 64 + c], w1 = we_w[4096 + k * 64 + c];
    unsigned short h0 = f2bf(w0), h1b = f2bf(w1);
    WT0h[c][k] = h0; WT0l[c][k] = f2bf(w0 - bf2f(h0));
    WT1h[c][k] = h1b; WT1l[c][k] = f2bf(w1 - bf2f(h1b));
  }
  __syncthreads();

  int wave = threadIdx.x >> 6, lane = threadIdx.x & 63;
  int l15 = lane & 15, g = lane >> 4;
  int rowbase = n0 + wave * 64;

  // ---- adjacency bits for 4 row-tiles ----
  union BWU { uint4 v[4]; unsigned w[16]; };
  BWU bw0, bw1, bw2, bw3;
  {
    const unsigned* p0 =
        bits + (size_t)br * 524288 + ((size_t)b * 512 + rowbase + l15) * 16;
    #pragma unroll
    for (int q = 0; q < 4; ++q) {
      bw0.v[q] = reinterpret_cast<const uint4*>(p0)[q];
      bw1.v[q] = reinterpret_cast<const uint4*>(p0 + 256)[q];
      bw2.v[q] = reinterpret_cast<const uint4*>(p0 + 512)[q];
      bw3.v[q] = reinterpret_cast<const uint4*>(p0 + 768)[q];
    }
  }

  float tv[4][4][4];   // t values, [row-tile][ct][r]

  if constexpr (!AIN8) {
    size_t xtbase = (size_t)(br * 64 + b) * 64 * 512;
    f32x4 acc[4][4] = {};
    #pragma unroll
    for (int kk = 0; kk < 512; kk += 32) {
      u16x8 a0, a1, a2, a3;
      {
        unsigned w0 = bw0.w[kk >> 5] >> (g * 8), w1 = bw1.w[kk >> 5] >> (g * 8);
        unsigned w2 = bw2.w[kk >> 5] >> (g * 8), w3 = bw3.w[kk >> 5] >> (g * 8);
        union { unsigned u[4]; u16x8 v; } r0, r1, r2, r3;
        #pragma unroll
        for (int i = 0; i < 4; ++i) {
          r0.u[i] = (((w0 >> (2 * i)) & 1u) ? 0x3F80u : 0u) |
                    (((w0 >> (2 * i + 1)) & 1u) ? 0x3F800000u : 0u);
          r1.u[i] = (((w1 >> (2 * i)) & 1u) ? 0x3F80u : 0u) |
                    (((w1 >> (2 * i + 1)) & 1u) ? 0x3F800000u : 0u);
          r2.u[i] = (((w2 >> (2 * i)) & 1u) ? 0x3F80u : 0u) |
                    (((w2 >> (2 * i + 1)) & 1u) ? 0x3F800000u : 0u);
          r3.u[i] = (((w3 >> (2 * i)) & 1u) ? 0x3F80u : 0u) |
                    (((w3 >> (2 * i + 1)) & 1u) ? 0x3F800000u : 0u);
        }
        a0 = r0.v; a1 = r1.v; a2 = r2.v; a3 = r3.v;
      }
      #pragma unroll
      for (int ct = 0; ct < 4; ++ct) {
        size_t off = xtbase + (size_t)(ct * 16 + l15) * 512 + kk + g * 8;
        u16x8 bh = *reinterpret_cast<const u16x8*>(XTbfh + off);
        u16x8 bl = *reinterpret_cast<const u16x8*>(XTbfl + off);
        acc[0][ct] = mfma16(a0, bh, acc[0][ct]);
        acc[0][ct] = mfma16(a0, bl, acc[0][ct]);
        acc[1][ct] = mfma16(a1, bh, acc[1][ct]);
        acc[1][ct] = mfma16(a1, bl, acc[1][ct]);
        acc[2][ct] = mfma16(a2, bh, acc[2][ct]);
        acc[2][ct] = mfma16(a2, bl, acc[2][ct]);
        acc[3][ct] = mfma16(a3, bh, acc[3][ct]);
        acc[3][ct] = mfma16(a3, bl, acc[3][ct]);
      }
    }
    #pragma unroll
    for (int rt = 0; rt < 4; ++rt)
      #pragma unroll
      for (int ct = 0; ct < 4; ++ct)
        #pragma unroll
        for (int r = 0; r < 4; ++r)
          tv[rt][ct][r] = acc[rt][ct][r];
  } else {
    size_t x8base = (size_t)(br * 64 + b) * 64 * 512;
    i32x4 acch[4][4] = {};
    i32x4 accl[4][4] = {};
    #pragma unroll
    for (int c64 = 0; c64 < 8; ++c64) {
      int kk = c64 * 64;
      int wi = (kk >> 5) + (g >> 1), shv = (g & 1) * 16;
      uint4 a0 = expand16((bw0.w[wi] >> shv) & 0xFFFFu);
      uint4 a1 = expand16((bw1.w[wi] >> shv) & 0xFFFFu);
      uint4 a2 = expand16((bw2.w[wi] >> shv) & 0xFFFFu);
      uint4 a3 = expand16((bw3.w[wi] >> shv) & 0xFFFFu);
      #pragma unroll
      for (int ct = 0; ct < 4; ++ct) {
        size_t off = x8base + (size_t)(ct * 16 + l15) * 512 + kk + g * 16;
        uint4 bh = *reinterpret_cast<const uint4*>(X8h_in + off);
        uint4 bl = *reinterpret_cast<const uint4*>(X8l_in + off);
        acch[0][ct] = mfma8(a0, bh, acch[0][ct]);
        accl[0][ct] = mfma8(a0, bl, accl[0][ct]);
        acch[1][ct] = mfma8(a1, bh, acch[1][ct]);
        accl[1][ct] = mfma8(a1, bl, accl[1][ct]);
        acch[2][ct] = mfma8(a2, bh, acch[2][ct]);
        accl[2][ct] = mfma8(a2, bl, accl[2][ct]);
        acch[3][ct] = mfma8(a3, bh, acch[3][ct]);
        accl[3][ct] = mfma8(a3, bl, accl[3][ct]);
      }
    }
    #pragma unroll
    for (int rt = 0; rt < 4; ++rt)
      #pragma unroll
      for (int ct = 0; ct < 4; ++ct)
        #pragma unroll
        for (int r = 0; r < 4; ++r)
          tv[rt][ct][r] = (float)acch[rt][ct][r] * (1.f / 127.f) +
                          (float)accl[rt][ct][r] * (1.f / 16129.f);
  }

  float sacc[4] = {0.f, 0.f, 0.f, 0.f};

  #pragma unroll
  for (int p = 0; p < 2; ++p) {
    if (!LAST && p) __syncthreads();   // prev pass's store read xh8 before ts reuse

    // stage t rows (pass p covers row-tiles 2p, 2p+1); wave-local ordering
    #pragma unroll
    for (int rt = 0; rt < 2; ++rt)
      #pragma unroll
      for (int ct = 0; ct < 4; ++ct)
        #pragma unroll
        for (int r = 0; r < 4; ++r)
          ts[wave][rt * 16 + g * 4 + r][ct * 16 + l15] = tv[2 * p + rt][ct][r];

    // ---- embed layer 1 ----
    f32x4 acc1[2][4] = {};
    #pragma unroll
    for (int kk = 0; kk < 64; kk += 32) {
      u16x8 ah[2], al[2];
      #pragma unroll
      for (int rt = 0; rt < 2; ++rt)
        split8(&ts[wave][rt * 16 + l15][kk + g * 8], ah[rt], al[rt]);
      #pragma unroll
      for (int ct = 0; ct < 4; ++ct) {
        u16x8 wh = *reinterpret_cast<const u16x8*>(&WT0h[ct * 16 + l15][kk + g * 8]);
        u16x8 wl = *reinterpret_cast<const u16x8*>(&WT0l[ct * 16 + l15][kk + g * 8]);
        #pragma unroll
        for (int rt = 0; rt < 2; ++rt) {
          acc1[rt][ct] = mfma16(ah[rt], wh, acc1[rt][ct]);
          acc1[rt][ct] = mfma16(al[rt], wh, acc1[rt][ct]);
          acc1[rt][ct] = mfma16(ah[rt], wl, acc1[rt][ct]);
        }
      }
    }
    #pragma unroll
    for (int rt = 0; rt < 2; ++rt)
      #pragma unroll
      for (int ct = 0; ct < 4; ++ct) {
        float bv = we_b[ct * 16 + l15];
        #pragma unroll
        for (int r = 0; r < 4; ++r)
          ts[wave][rt * 16 + g * 4 + r][ct * 16 + l15] =
              fmaxf(acc1[rt][ct][r] + bv, 0.f);
      }

    // ---- embed layer 2 ----
    f32x4 acc2[2][4] = {};
    #pragma unroll
    for (int kk = 0; kk < 64; kk += 32) {
      u16x8 ah[2], al[2];
      #pragma unroll
      for (int rt = 0; rt < 2; ++rt)
        split8(&ts[wave][rt * 16 + l15][kk + g * 8], ah[rt], al[rt]);
      #pragma unroll
      for (int ct = 0; ct < 4; ++ct) {
        u16x8 wh = *reinterpret_cast<const u16x8*>(&WT1h[ct * 16 + l15][kk + g * 8]);
        u16x8 wl = *reinterpret_cast<const u16x8*>(&WT1l[ct * 16 + l15][kk + g * 8]);
        #pragma unroll
        for (int rt = 0; rt < 2; ++rt) {
          acc2[rt][ct] = mfma16(ah[rt], wh, acc2[rt][ct]);
          acc2[rt][ct] = mfma16(al[rt], wh, acc2[rt][ct]);
          acc2[rt][ct] = mfma16(ah[rt], wl, acc2[rt][ct]);
        }
      }
    }

    const float* bbrow =
        bb + ((size_t)(br * 64 + b) * 512 + rowbase + p * 32) * 64;

    if (!LAST) {
      __syncthreads();   // all waves done with ts before xh8/xl8 alias reuse
      #pragma unroll
      for (int rt = 0; rt < 2; ++rt)
        #pragma unroll
        for (int ct = 0; ct < 4; ++ct) {
          float bv = we_b[64 + ct * 16 + l15];
          #pragma unroll
          for (int r = 0; r < 4; ++r) {
            int rr = rt * 16 + g * 4 + r, cc = ct * 16 + l15;
            float t3 = fmaxf(acc2[rt][ct][r] + bv, 0.f);
            float v = tanh_fast(bbrow[rr * 64 + cc] + t3);
            float s = v * 127.f;
            float qhf = rintf(s);
            float qlf = rintf((s - qhf) * 127.f);
            xh8[wave * 32 + rr][cc] = (char)(int)qhf;
            xl8[wave * 32 + rr][cc] = (char)(int)qlf;
          }
        }
      __syncthreads();
      // transpose store: thread (c, w4) stores 32 n-bytes for column c
      int c = threadIdx.x >> 2, w4 = threadIdx.x & 3;
      int j0 = w4 * 32;
      size_t base = ((size_t)(br * 64 + b) * 64 + c) * 512 + n0 + w4 * 64 + p * 32;
      union { uint4 v[2]; char bch[32]; } oh, ol;
      #pragma unroll
      for (int i = 0; i < 32; ++i) {
        oh.bch[i] = xh8[j0 + i][c];
        ol.bch[i] = xl8[j0 + i][c];
      }
      *reinterpret_cast<uint4*>(X8h_out + base) = oh.v[0];
      *reinterpret_cast<uint4*>(X8h_out + base + 16) = oh.v[1];
      *reinterpret_cast<uint4*>(X8l_out + base) = ol.v[0];
      *reinterpret_cast<uint4*>(X8l_out + base + 16) = ol.v[1];
    } else {
      #pragma unroll
      for (int ct = 0; ct < 4; ++ct) {
        float bv = we_b[64 + ct * 16 + l15];
        float s = 0.f;
        #pragma unroll
        for (int rt = 0; rt < 2; ++rt)
          #pragma unroll
          for (int r = 0; r < 4; ++r) {
            int rr = rt * 16 + g * 4 + r, cc = ct * 16 + l15;
            float t3 = fmaxf(acc2[rt][ct][r] + bv, 0.f);
            s += tanh_fast(bbrow[rr * 64 + cc] + t3);
          }
        sacc[ct] += s;
      }
    }
  }

  if (LAST) {
    #pragma unroll
    for (int ct = 0; ct < 4; ++ct)
      colsum[wave * 4 + g][ct * 16 + l15] = sacc[ct];
    __syncthreads();
    if (threadIdx.x < 64) {
      float s = 0.f;
      #pragma unroll
      for (int q = 0; q < 16; ++q) s += colsum[q][threadIdx.x];
      Spart[((size_t)(br * 64 + b) * 2 + rb) * 64 + threadIdx.x] = s;
    }
  }
}

// ---------- final: e = S@wout + bout ; cosine ----------
__global__ __launch_bounds__(64) void k_final(const float* __restrict__ Spart,
                                              const float* __restrict__ wout,
                                              const float* __restrict__ bout,
                                              float* __restrict__ out) {
  int b = blockIdx.x, c = threadIdx.x;
  __shared__ float s1s[64], s2s[64];
  float s1 = 0.f, s2 = 0.f;
  #pragma unroll
  for (int tl = 0; tl < 2; ++tl) {
    s1 += Spart[((size_t)(0 * 64 + b) * 2 + tl) * 64 + c];
    s2 += Spart[((size_t)(1 * 64 + b) * 2 + tl) * 64 + c];
  }
  s1s[c] = s1; s2s[c] = s2;
  __syncthreads();
  float e1 = bout[c], e2 = bout[c];
  for (int k = 0; k < 64; ++k) {
    float w = wout[k * 64 + c];
    e1 += s1s[k] * w;
    e2 += s2s[k] * w;
  }
  float nm = e1 * e2, dA = e1 * e1, dB = e2 * e2;
  #pragma unroll
  for (int off = 32; off; off >>= 1) {
    nm += __shfl_xor(nm, off);
    dA += __shfl_xor(dA, off);
    dB += __shfl_xor(dB, off);
  }
  if (c == 0) out[b] = nm / sqrtf(dA * dB + 1e-10f);
}

// ---------- launch ----------
extern "C" void kernel_launch(void* const* d_in, const int* in_sizes, int n_in,
                              void* d_out, int out_size, void* d_ws, size_t ws_size,
                              hipStream_t stream) {
  const int*   cfg1 = (const int*)d_in[0];
  const float* lit1 = (const float*)d_in[2];
  const float* sem1 = (const float*)d_in[3];
  const int*   cfg2 = (const int*)d_in[4];
  const float* lit2 = (const float*)d_in[6];
  const float* sem2 = (const float*)d_in[7];
  const float* d1w1 = (const float*)d_in[8];
  const float* d1b1 = (const float*)d_in[9];
  const float* d2w1 = (const float*)d_in[10];
  const float* d2b1 = (const float*)d_in[11];
  const float* lk1  = (const float*)d_in[12];
  const float* lrk1 = (const float*)d_in[13];
  const float* lb1  = (const float*)d_in[14];
  const float* d1w2 = (const float*)d_in[15];
  const float* d1b2 = (const float*)d_in[16];
  const float* d2w2 = (const float*)d_in[17];
  const float* d2b2 = (const float*)d_in[18];
  const float* lk2  = (const float*)d_in[19];
  const float* lrk2 = (const float*)d_in[20];
  const float* lb2  = (const float*)d_in[21];
  const float* we_w = (const float*)d_in[22];
  const float* we_b = (const float*)d_in[23];
  const float* wout = (const float*)d_in[24];
  const float* bout = (const float*)d_in[25];

  char* ws = (char*)d_ws;
  float* bb   = (float*)ws;                               // [2][32768][64]  0 .. 16.78M
  float* xk   = (float*)(ws + 16777216);                  // [2][32768][128] 16.78 .. 50.33M
  // post-LSTM aliases into dead xk:
  unsigned short* XTbfh = (unsigned short*)(ws + 16777216); // bf16 x0 hi, 8.39M
  unsigned short* XTbfl = (unsigned short*)(ws + 25165824); // bf16 x0 lo, 8.39M
  char* A8h = ws + 33554432;                              // i8 planes, 4.19M each
  char* A8l = ws + 37748736;
  char* B8h = ws + 41943040;
  char* B8l = ws + 46137344;                              // .. 50.33M
  float* Spart = (float*)(ws + 58720256);                 // 64 KB
  unsigned* bits = (unsigned*)(ws + 58982400);            // 4.19 MB

  // sem -> xk (must precede front; LSTM reads xk)
  k_ff<64, 128, 0><<<512, 256, 0, stream>>>(sem1, sem2, lk1, lk2, lb1, lb2,
                                            xk, 128, 4194304L);

  // LSTM (critical path) ∥ pack ∥ lit-MLP — separate block ranges
  k_front<<<800, 256, 0, stream>>>(xk, lrk1, lrk2, bb, cfg1, cfg2, bits,
                                   lit1, lit2, d1w1, d1w2, d1b1, d1b2,
                                   d2w1, d2w2, d2b1, d2b2);

  k_relu_t<<<1024, 256, 0, stream>>>(bb, XTbfh, XTbfl);   // xk now dead

  // it0: bf16 in -> i8 out ; it1-3: i8 ping-pong ; it4: i8 in, colsums
  k_iter<0, 0><<<256, 256, 0, stream>>>(bits, XTbfh, XTbfl, nullptr, nullptr,
                                        bb, we_w, we_b, A8h, A8l, Spart);
  k_iter<1, 0><<<256, 256, 0, stream>>>(bits, nullptr, nullptr, A8h, A8l,
                                        bb, we_w, we_b, B8h, B8l, Spart);
  k_iter<1, 0><<<256, 256, 0, stream>>>(bits, nullptr, nullptr, B8h, B8l,
                                        bb, we_w, we_b, A8h, A8l, Spart);
  k_iter<1, 0><<<256, 256, 0, stream>>>(bits, nullptr, nullptr, A8h, A8l,
                                        bb, we_w, we_b, B8h, B8l, Spart);
  k_iter<1, 1><<<256, 256, 0, stream>>>(bits, nullptr, nullptr, B8h, B8l,
                                        bb, we_w, we_b, A8h, A8l, Spart);

  k_final<<<64, 64, 0, stream>>>(Spart, wout, bout, (float*)d_out);
}